// Round 1
// baseline (1052.029 us; speedup 1.0000x reference)
//
#include <hip/hip_runtime.h>
#include <hip/hip_bf16.h>

#define B_ 2
#define N_ 256
#define IN_ 256
#define H_ 8
#define D_ 64
#define HD_ 512
#define ALPHA_ 0.2f
#define LN_EPS_ 1e-5f

__device__ __forceinline__ float wave_sum64(float v){
  v += __shfl_xor(v, 1);  v += __shfl_xor(v, 2);  v += __shfl_xor(v, 4);
  v += __shfl_xor(v, 8);  v += __shfl_xor(v, 16); v += __shfl_xor(v, 32);
  return v;
}

// K1: h_s = (emb_node*mask) @ Ws, h_t = ... @ Wt   (B*N=512 rows, 256->512)
__global__ __launch_bounds__(512) void k1_hst(
    const float* __restrict__ emb_node, const float* __restrict__ node_mask,
    const float* __restrict__ Ws, const float* __restrict__ Wt,
    float* __restrict__ hs, float* __restrict__ ht)
{
  int t = threadIdx.x;              // output col 0..511
  int row0 = blockIdx.x * 4;        // flat b*N+i
  __shared__ float x[4][IN_];
  if (t < 256){
    #pragma unroll
    for (int r = 0; r < 4; ++r)
      x[r][t] = emb_node[(size_t)(row0 + r)*IN_ + t] * node_mask[row0 + r];
  }
  __syncthreads();
  float as[4] = {0,0,0,0}, at[4] = {0,0,0,0};
  for (int k = 0; k < IN_; ++k){
    float wsv = Ws[(size_t)k*HD_ + t];
    float wtv = Wt[(size_t)k*HD_ + t];
    #pragma unroll
    for (int r = 0; r < 4; ++r){
      as[r] += x[r][k]*wsv;
      at[r] += x[r][k]*wtv;
    }
  }
  #pragma unroll
  for (int r = 0; r < 4; ++r){
    hs[(size_t)(row0 + r)*HD_ + t] = as[r];
    ht[(size_t)(row0 + r)*HD_ + t] = at[r];
  }
}

// K2: fused h_e GEMM + leaky_relu + attn-dot + exp -> scores[B][H][N_i][N_j]
// grid (B*N, H/2), block 512 (8 waves: 4 waves/head, 64 rows/wave, 64 cols=1 head)
__global__ __launch_bounds__(512) void k2_scores(
    const float* __restrict__ emb_edge, const float* __restrict__ adj,
    const float* __restrict__ node_mask, const float* __restrict__ We,
    const float* __restrict__ hs, const float* __restrict__ ht,
    const float* __restrict__ attn, float* __restrict__ scores)
{
  int bi = blockIdx.x; int b = bi >> 8, i = bi & 255;
  int hp = blockIdx.y;                       // head pair
  int tid = threadIdx.x;
  int w = tid >> 6, lane = tid & 63;
  int head = hp*2 + (w >> 2);
  int wrow0 = (w & 3) * 64;
  int lrow = lane >> 4, lcol = lane & 15;

  __shared__ float A[256][16];               // xe rows x k-chunk
  __shared__ float Bt[16][128];              // We k-chunk x 2 heads
  __shared__ float mj[256];

  if (tid < 256) mj[tid] = node_mask[b*N_ + tid];

  float acc[16][4];
  #pragma unroll
  for (int r = 0; r < 16; ++r)
    #pragma unroll
    for (int c = 0; c < 4; ++c) acc[r][c] = 0.f;

  const float* Abase = emb_edge + (size_t)bi * N_ * IN_;

  for (int k0 = 0; k0 < IN_; k0 += 16){
    __syncthreads();
    { // stage A: 256x16 = 4096 floats, 8 per thread
      int f = tid * 8;
      int row = f >> 4, kk = f & 15;         // kk in {0,8}
      const float4* src = (const float4*)(Abase + (size_t)row*IN_ + k0 + kk);
      float4 v0 = src[0], v1 = src[1];
      float4* dst = (float4*)(&A[row][kk]);
      dst[0] = v0; dst[1] = v1;
    }
    { // stage Bt: 16x128 = 2048 floats, 4 per thread
      int f = tid * 4;
      int kk = f >> 7, c = f & 127;
      *(float4*)(&Bt[kk][c]) = *(const float4*)(We + (size_t)(k0 + kk)*HD_ + hp*128 + c);
    }
    __syncthreads();
    #pragma unroll
    for (int k = 0; k < 16; ++k){
      float bv[4];
      #pragma unroll
      for (int c = 0; c < 4; ++c) bv[c] = Bt[k][(w >> 2)*64 + lcol + 16*c];
      #pragma unroll
      for (int r = 0; r < 16; ++r){
        float av = A[wrow0 + lrow + 4*r][k];
        #pragma unroll
        for (int c = 0; c < 4; ++c) acc[r][c] += av * bv[c];
      }
    }
  }

  // epilogue: per row j, score = exp(sum_d attn*lrelu(m*acc + hs + ht)) * adj * emask
  float mi = node_mask[b*N_ + i];
  float attnv[4], hsv[4];
  #pragma unroll
  for (int c = 0; c < 4; ++c){
    attnv[c] = attn[head*D_ + lcol + 16*c];
    hsv[c]   = hs[(size_t)bi*HD_ + head*D_ + lcol + 16*c];
  }
  float expo = 0.f;
  #pragma unroll
  for (int r = 0; r < 16; ++r){
    int j = wrow0 + lrow + 4*r;
    float m = mi * mj[j];
    const float* htj = ht + (size_t)(b*N_ + j)*HD_ + head*D_;
    float p = 0.f;
    #pragma unroll
    for (int c = 0; c < 4; ++c){
      float v = m*acc[r][c] + hsv[c] + htj[lcol + 16*c];
      v = v > 0.f ? v : ALPHA_*v;
      p += attnv[c]*v;
    }
    p += __shfl_xor(p, 1); p += __shfl_xor(p, 2);
    p += __shfl_xor(p, 4); p += __shfl_xor(p, 8);
    if (r == lcol) expo = p;
  }
  int jw = wrow0 + lrow + 4*lcol;
  float mw = mi * mj[jw];
  float sc = expf(expo) * adj[(size_t)bi*N_ + jw] * mw;
  scores[(((size_t)b*H_ + head)*N_ + i)*N_ + jw] = sc;
}

// K3a: invd[b,h,i] = 1/(sum_j scores + 1e-6)
__global__ __launch_bounds__(256) void k3a_denom(
    const float* __restrict__ scores, float* __restrict__ invd)
{
  int row = blockIdx.x*4 + (threadIdx.x >> 6);   // (b*H+h)*N + i
  int lane = threadIdx.x & 63;
  const float* s = scores + (size_t)row*256;
  float v = s[lane] + s[lane+64] + s[lane+128] + s[lane+192];
  v = wave_sum64(v);
  if (lane == 0) invd[row] = 1.0f/(v + 1e-6f);
}

// K3b: nn[b,i,d] = sum_h sum_j p * h_t[b,j,h,d]
__global__ __launch_bounds__(256) void k3b_nn(
    const float* __restrict__ scores, const float* __restrict__ invd,
    const float* __restrict__ ht, float* __restrict__ nn)
{
  int bi = blockIdx.x; int b = bi >> 8, i = bi & 255;
  int w = threadIdx.x >> 6, lane = threadIdx.x & 63;
  float acc = 0.f;
  for (int h = 0; h < H_; ++h){
    float iv = invd[(b*H_ + h)*N_ + i];
    const float* srow = scores + (((size_t)b*H_ + h)*N_ + i)*N_;
    const float* htb = ht + (size_t)b*N_*HD_ + h*D_ + lane;
    #pragma unroll 4
    for (int jj = 0; jj < 64; ++jj){
      int j = w*64 + jj;
      acc += srow[j]*iv * htb[(size_t)j*HD_];
    }
  }
  __shared__ float part[4][64];
  part[w][lane] = acc;
  __syncthreads();
  if (threadIdx.x < 64)
    nn[(size_t)bi*D_ + threadIdx.x] = part[0][threadIdx.x] + part[1][threadIdx.x]
                                    + part[2][threadIdx.x] + part[3][threadIdx.x];
}

// K4: r = nn@Wn+bn; out_node = LN(xn + r); a_row = r@W1; a_col = r@W2
__global__ __launch_bounds__(256) void k4_node(
    const float* __restrict__ emb_node, const float* __restrict__ node_mask,
    const float* __restrict__ nn, const float* __restrict__ Wn,
    const float* __restrict__ bn, const float* __restrict__ Wedge,
    const float* __restrict__ gx, const float* __restrict__ bx,
    float* __restrict__ a_row, float* __restrict__ a_col,
    float* __restrict__ out_node)
{
  int bi = blockIdx.x; int t = threadIdx.x;
  int w = t >> 6, lane = t & 63;
  __shared__ float nl[64];
  __shared__ float rl[256];
  __shared__ float red[4];
  if (t < 64) nl[t] = nn[(size_t)bi*D_ + t];
  __syncthreads();
  float acc = bn[t];
  #pragma unroll 4
  for (int d = 0; d < 64; ++d) acc += nl[d]*Wn[(size_t)d*IN_ + t];
  rl[t] = acc;
  float y = emb_node[(size_t)bi*IN_ + t]*node_mask[bi] + acc;
  float s = wave_sum64(y);
  if (lane == 0) red[w] = s;
  __syncthreads();
  float mean = (red[0]+red[1]+red[2]+red[3]) * (1.f/256.f);
  float dv = y - mean;
  float s2 = wave_sum64(dv*dv);
  __syncthreads();
  if (lane == 0) red[w] = s2;
  __syncthreads();
  float var = (red[0]+red[1]+red[2]+red[3]) * (1.f/256.f);
  out_node[(size_t)bi*IN_ + t] = dv * (1.0f/sqrtf(var + LN_EPS_)) * gx[t] + bx[t];
  float ar = 0.f, ac = 0.f;
  #pragma unroll 4
  for (int k = 0; k < 256; ++k){
    float rv = rl[k];
    ar += rv*Wedge[(size_t)k*IN_ + t];
    ac += rv*Wedge[(size_t)(k + 256)*IN_ + t];
  }
  a_row[(size_t)bi*IN_ + t] = ar;
  a_col[(size_t)bi*IN_ + t] = ac;
}

// K5: out_edge = LN(xe + a_row(i) + a_col(j) + xe@W3 + bedge)
// grid B*N*N/64, block 256 (4 waves x 16 rows, 256 cols)
__global__ __launch_bounds__(256) void k5_edge(
    const float* __restrict__ emb_edge, const float* __restrict__ node_mask,
    const float* __restrict__ Wedge, const float* __restrict__ bedge,
    const float* __restrict__ a_row, const float* __restrict__ a_col,
    const float* __restrict__ ge, const float* __restrict__ be,
    float* __restrict__ out_edge)
{
  int tid = threadIdx.x;
  int w = tid >> 6, lane = tid & 63;
  size_t fbase = (size_t)blockIdx.x * 64;     // flat (b,i,j) row base
  int b = (int)(fbase >> 16);
  int i = (int)((fbase >> 8) & 255);
  int j0 = (int)(fbase & 255);

  __shared__ float A[64][16];
  __shared__ float Bt[16][256];
  __shared__ float arow_l[256], bedge_l[256], ge_l[256], be_l[256];

  arow_l[tid]  = a_row[(size_t)(b*N_ + i)*IN_ + tid];
  bedge_l[tid] = bedge[tid];
  ge_l[tid]    = ge[tid];
  be_l[tid]    = be[tid];

  const float* W3 = Wedge + (size_t)512*IN_;
  const float* Abase = emb_edge + fbase*IN_;

  float acc[16][4];
  #pragma unroll
  for (int r = 0; r < 16; ++r)
    #pragma unroll
    for (int c = 0; c < 4; ++c) acc[r][c] = 0.f;

  for (int k0 = 0; k0 < IN_; k0 += 16){
    __syncthreads();
    { // stage A: 64x16 = 1024 floats
      int f = tid * 4; int row = f >> 4, kk = f & 15;
      *(float4*)(&A[row][kk]) = *(const float4*)(Abase + (size_t)row*IN_ + k0 + kk);
    }
    #pragma unroll
    for (int q = 0; q < 4; ++q){ // stage Bt: 16x256 = 4096 floats
      int f = tid*4 + q*1024; int kk = f >> 8, c = f & 255;
      *(float4*)(&Bt[kk][c]) = *(const float4*)(W3 + (size_t)(k0 + kk)*IN_ + c);
    }
    __syncthreads();
    #pragma unroll
    for (int k = 0; k < 16; ++k){
      float bv[4];
      #pragma unroll
      for (int c = 0; c < 4; ++c) bv[c] = Bt[k][lane + 64*c];
      #pragma unroll
      for (int r = 0; r < 16; ++r){
        float av = A[w*16 + r][k];
        #pragma unroll
        for (int c = 0; c < 4; ++c) acc[r][c] += av * bv[c];
      }
    }
  }

  float mi = node_mask[b*N_ + i];
  #pragma unroll
  for (int r = 0; r < 16; ++r){
    int jl = w*16 + r;
    int j = j0 + jl;
    float m = mi * node_mask[b*N_ + j];
    size_t frow = fbase + jl;
    const float* xer = emb_edge + frow*IN_;
    const float* acj = a_col + (size_t)(b*N_ + j)*IN_;
    float y[4];
    float s = 0.f;
    #pragma unroll
    for (int c = 0; c < 4; ++c){
      int col = lane + 64*c;
      y[c] = m*(xer[col] + acc[r][c]) + arow_l[col] + acj[col] + bedge_l[col];
      s += y[c];
    }
    s = wave_sum64(s);
    float mean = s * (1.f/256.f);
    float s2 = 0.f;
    #pragma unroll
    for (int c = 0; c < 4; ++c){ float d = y[c] - mean; s2 += d*d; }
    s2 = wave_sum64(s2);
    float rstd = 1.0f/sqrtf(s2*(1.f/256.f) + LN_EPS_);
    #pragma unroll
    for (int c = 0; c < 4; ++c){
      int col = lane + 64*c;
      out_edge[frow*IN_ + col] = (y[c] - mean)*rstd*ge_l[col] + be_l[col];
    }
  }
}

extern "C" void kernel_launch(void* const* d_in, const int* in_sizes, int n_in,
                              void* d_out, int out_size, void* d_ws, size_t ws_size,
                              hipStream_t stream)
{
  const float* emb_node  = (const float*)d_in[0];
  const float* emb_edge  = (const float*)d_in[1];
  const float* adj       = (const float*)d_in[2];
  const float* node_mask = (const float*)d_in[3];
  const float* Ws    = (const float*)d_in[4];
  const float* Wt    = (const float*)d_in[5];
  const float* We    = (const float*)d_in[6];
  const float* attn  = (const float*)d_in[7];
  const float* Wn    = (const float*)d_in[8];
  const float* bn    = (const float*)d_in[9];
  const float* Wedge = (const float*)d_in[10];
  const float* bedge = (const float*)d_in[11];
  const float* gx    = (const float*)d_in[12];
  const float* bx    = (const float*)d_in[13];
  const float* ge    = (const float*)d_in[14];
  const float* be    = (const float*)d_in[15];

  float* ws     = (float*)d_ws;
  float* hs     = ws;                   // 262144
  float* ht     = hs + 262144;          // 262144
  float* scores = ht + 262144;          // 1048576  [B][H][N][N]
  float* invd   = scores + 1048576;     // 4096
  float* nn     = invd + 4096;          // 32768
  float* a_row  = nn + 32768;           // 131072
  float* a_col  = a_row + 131072;       // 131072

  float* out_node = (float*)d_out;
  float* out_edge = out_node + (size_t)B_*N_*IN_;

  k1_hst  <<<128, 512, 0, stream>>>(emb_node, node_mask, Ws, Wt, hs, ht);
  k2_scores<<<dim3(B_*N_, H_/2), 512, 0, stream>>>(emb_edge, adj, node_mask, We,
                                                   hs, ht, attn, scores);
  k3a_denom<<<(B_*H_*N_)/4, 256, 0, stream>>>(scores, invd);
  k3b_nn  <<<B_*N_, 256, 0, stream>>>(scores, invd, ht, nn);
  k4_node <<<B_*N_, 256, 0, stream>>>(emb_node, node_mask, nn, Wn, bn, Wedge,
                                      gx, bx, a_row, a_col, out_node);
  k5_edge <<<(B_*N_*N_)/64, 256, 0, stream>>>(emb_edge, node_mask, Wedge, bedge,
                                              a_row, a_col, ge, be, out_edge);
}

// Round 2
// 646.166 us; speedup vs baseline: 1.6281x; 1.6281x over previous
//
#include <hip/hip_runtime.h>
#include <hip/hip_bf16.h>

#define B_ 2
#define N_ 256
#define IN_ 256
#define H_ 8
#define D_ 64
#define HD_ 512
#define ALPHA_ 0.2f
#define LN_EPS_ 1e-5f

typedef __attribute__((ext_vector_type(8))) short bf16x8;
typedef __attribute__((ext_vector_type(16))) float f32x16;

#define LSTR 24   // ushorts per LDS row: 16 data + 8 pad (48B, 16B-aligned)

__device__ __forceinline__ int swoff(int r, int g){
  return r*LSTR + ((g ^ ((r>>3)&1))<<3);   // ushort units; granule = 8 bf16 = 16B
}

__device__ __forceinline__ unsigned short f2bf(float x){
  unsigned int u = __float_as_uint(x);
  u += 0x7fff + ((u>>16)&1);
  return (unsigned short)(u>>16);
}
__device__ __forceinline__ float bf2f(unsigned short h){
  return __uint_as_float(((unsigned int)h)<<16);
}

__device__ __forceinline__ f32x16 mm(bf16x8 a, bf16x8 b, f32x16 c){
  return __builtin_amdgcn_mfma_f32_32x32x16_bf16(a, b, c, 0, 0, 0);
}

__device__ __forceinline__ float wave_sum64(float v){
  v += __shfl_xor(v, 1);  v += __shfl_xor(v, 2);  v += __shfl_xor(v, 4);
  v += __shfl_xor(v, 8);  v += __shfl_xor(v, 16); v += __shfl_xor(v, 32);
  return v;
}

union U8 { unsigned short u[8]; uint4 v; };

// k0: WeT[512][256] hi/lo from We[256][512]; W3T[256][256] hi/lo from Wedge rows 512..767
__global__ __launch_bounds__(256) void k0_wprep(
    const float* __restrict__ We, const float* __restrict__ Wedge,
    unsigned short* __restrict__ WeT_hi, unsigned short* __restrict__ WeT_lo,
    unsigned short* __restrict__ W3T_hi, unsigned short* __restrict__ W3T_lo)
{
  int rb = blockIdx.x, t = threadIdx.x;
  if (rb < 512){
    float x = We[(size_t)t*HD_ + rb];
    unsigned short hb = f2bf(x);
    WeT_hi[(size_t)rb*IN_ + t] = hb;
    WeT_lo[(size_t)rb*IN_ + t] = f2bf(x - bf2f(hb));
  } else {
    int c = rb - 512;
    float x = Wedge[(size_t)(512 + t)*IN_ + c];
    unsigned short hb = f2bf(x);
    W3T_hi[(size_t)c*IN_ + t] = hb;
    W3T_lo[(size_t)c*IN_ + t] = f2bf(x - bf2f(hb));
  }
}

// K1: h_s/h_t projections + htT transpose
__global__ __launch_bounds__(512) void k1_hst(
    const float* __restrict__ emb_node, const float* __restrict__ node_mask,
    const float* __restrict__ Ws, const float* __restrict__ Wt,
    float* __restrict__ hs, float* __restrict__ ht, float* __restrict__ htT)
{
  int t = threadIdx.x;
  int row0 = blockIdx.x * 4;
  __shared__ float x[4][IN_];
  if (t < 256){
    #pragma unroll
    for (int r = 0; r < 4; ++r)
      x[r][t] = emb_node[(size_t)(row0 + r)*IN_ + t] * node_mask[row0 + r];
  }
  __syncthreads();
  float as[4] = {0,0,0,0}, at[4] = {0,0,0,0};
  for (int k = 0; k < IN_; ++k){
    float wsv = Ws[(size_t)k*HD_ + t];
    float wtv = Wt[(size_t)k*HD_ + t];
    #pragma unroll
    for (int r = 0; r < 4; ++r){
      as[r] += x[r][k]*wsv;
      at[r] += x[r][k]*wtv;
    }
  }
  #pragma unroll
  for (int r = 0; r < 4; ++r){
    int row = row0 + r;
    hs[(size_t)row*HD_ + t] = as[r];
    ht[(size_t)row*HD_ + t] = at[r];
    htT[((size_t)(row>>8)*HD_ + t)*N_ + (row&255)] = at[r];
  }
}

// K2: scores via split-bf16 MFMA, swapped operands: D[hd][j] = WeT . xe^T
__global__ __launch_bounds__(512) void k2_scores(
    const float* __restrict__ emb_edge, const float* __restrict__ adj,
    const float* __restrict__ node_mask,
    const unsigned short* __restrict__ WeT_hi, const unsigned short* __restrict__ WeT_lo,
    const float* __restrict__ hs, const float* __restrict__ htT,
    const float* __restrict__ attn, float* __restrict__ scores)
{
  int bi = blockIdx.x, hp = blockIdx.y;
  int b = bi >> 8, i = bi & 255;
  int tid = threadIdx.x;
  int w = tid >> 6, l = tid & 63, h = l >> 5, ln = l & 31;
  int hl = w & 3;              // head within block
  int jb = (w >> 2) << 7;      // j base: 0 or 128

  __shared__ unsigned short Ah[256*LSTR], Al[256*LSTR], Bh[256*LSTR], Bl[256*LSTR];
  __shared__ float hs_l[256], at_l[256], mj_l[256];

  if (tid < 256){
    hs_l[tid] = hs[(size_t)bi*HD_ + (hp<<8) + tid];
    at_l[tid] = attn[(hp<<8) + tid];
    mj_l[tid] = node_mask[(b<<8) + tid];
  }

  f32x16 acc[2][4];
  #pragma unroll
  for (int t2 = 0; t2 < 2; ++t2)
    #pragma unroll
    for (int jt = 0; jt < 4; ++jt)
      #pragma unroll
      for (int e = 0; e < 16; ++e) acc[t2][jt][e] = 0.f;

  int r = tid & 255, sub = tid >> 8;
  const float* xrow = emb_edge + ((size_t)bi*N_ + r)*IN_;
  const unsigned short* asrc = (sub ? WeT_lo : WeT_hi) + ((size_t)((hp<<8) + r))*IN_;
  unsigned short* adst = sub ? Al : Ah;

  for (int k0 = 0; k0 < IN_; k0 += 16){
    __syncthreads();
    {
      uint4 v0 = *(const uint4*)(asrc + k0);
      uint4 v1 = *(const uint4*)(asrc + k0 + 8);
      *(uint4*)&adst[swoff(r, 0)] = v0;
      *(uint4*)&adst[swoff(r, 1)] = v1;
      const float4* bsrc = (const float4*)(xrow + k0 + sub*8);
      float4 q0 = bsrc[0], q1 = bsrc[1];
      float xs[8] = {q0.x,q0.y,q0.z,q0.w,q1.x,q1.y,q1.z,q1.w};
      U8 hh, ll;
      #pragma unroll
      for (int q = 0; q < 8; ++q){
        unsigned short hb = f2bf(xs[q]);
        hh.u[q] = hb;
        ll.u[q] = f2bf(xs[q] - bf2f(hb));
      }
      *(uint4*)&Bh[swoff(r, sub)] = hh.v;
      *(uint4*)&Bl[swoff(r, sub)] = ll.v;
    }
    __syncthreads();
    {
      int g = h;
      bf16x8 a0h = *(const bf16x8*)&Ah[swoff(hl*64 + ln, g)];
      bf16x8 a1h = *(const bf16x8*)&Ah[swoff(hl*64 + 32 + ln, g)];
      bf16x8 a0l = *(const bf16x8*)&Al[swoff(hl*64 + ln, g)];
      bf16x8 a1l = *(const bf16x8*)&Al[swoff(hl*64 + 32 + ln, g)];
      #pragma unroll
      for (int jt = 0; jt < 4; ++jt){
        int br = jb + jt*32 + ln;
        bf16x8 bh = *(const bf16x8*)&Bh[swoff(br, g)];
        bf16x8 bl = *(const bf16x8*)&Bl[swoff(br, g)];
        acc[0][jt] = mm(a0h, bh, acc[0][jt]);
        acc[0][jt] = mm(a0h, bl, acc[0][jt]);
        acc[0][jt] = mm(a0l, bh, acc[0][jt]);
        acc[1][jt] = mm(a1h, bh, acc[1][jt]);
        acc[1][jt] = mm(a1h, bl, acc[1][jt]);
        acc[1][jt] = mm(a1l, bh, acc[1][jt]);
      }
    }
  }

  float mi = node_mask[(b<<8) + i];
  int head = hp*4 + hl;
  const float* htb = htT + ((size_t)b*HD_ + (hp<<8) + hl*64)*N_;
  const float* adjr = adj + (size_t)bi*N_;
  #pragma unroll
  for (int jt = 0; jt < 4; ++jt){
    int j = jb + jt*32 + ln;
    float m = mi * mj_l[j];
    float es = 0.f;
    #pragma unroll
    for (int t2 = 0; t2 < 2; ++t2)
      #pragma unroll
      for (int rg = 0; rg < 16; ++rg){
        int hdl = t2*32 + (rg&3) + ((rg>>2)<<3) + (h<<2);
        float hv = htb[(size_t)hdl*N_ + j];
        float v = fmaf(m, acc[t2][jt][rg], hs_l[hl*64 + hdl] + hv);
        v = v > 0.f ? v : ALPHA_*v;
        es = fmaf(at_l[hl*64 + hdl], v, es);
      }
    es += __shfl_xor(es, 32);
    float sc = expf(es) * adjr[j] * m;
    if (h == 0)
      scores[(((size_t)(b*H_ + head))*N_ + i)*N_ + j] = sc;
  }
}

__global__ __launch_bounds__(256) void k3a_denom(
    const float* __restrict__ scores, float* __restrict__ invd)
{
  int row = blockIdx.x*4 + (threadIdx.x >> 6);
  int lane = threadIdx.x & 63;
  const float* s = scores + (size_t)row*256;
  float v = s[lane] + s[lane+64] + s[lane+128] + s[lane+192];
  v = wave_sum64(v);
  if (lane == 0) invd[row] = 1.0f/(v + 1e-6f);
}

__global__ __launch_bounds__(256) void k3b_nn(
    const float* __restrict__ scores, const float* __restrict__ invd,
    const float* __restrict__ ht, float* __restrict__ nn)
{
  int bi = blockIdx.x; int b = bi >> 8, i = bi & 255;
  int w = threadIdx.x >> 6, lane = threadIdx.x & 63;
  float acc = 0.f;
  for (int h = 0; h < H_; ++h){
    float iv = invd[(b*H_ + h)*N_ + i];
    const float* srow = scores + (((size_t)b*H_ + h)*N_ + i)*N_;
    const float* htb = ht + (size_t)b*N_*HD_ + h*D_ + lane;
    #pragma unroll 4
    for (int jj = 0; jj < 64; ++jj){
      int j = w*64 + jj;
      acc += srow[j]*iv * htb[(size_t)j*HD_];
    }
  }
  __shared__ float part[4][64];
  part[w][lane] = acc;
  __syncthreads();
  if (threadIdx.x < 64)
    nn[(size_t)bi*D_ + threadIdx.x] = part[0][threadIdx.x] + part[1][threadIdx.x]
                                    + part[2][threadIdx.x] + part[3][threadIdx.x];
}

__global__ __launch_bounds__(256) void k4_node(
    const float* __restrict__ emb_node, const float* __restrict__ node_mask,
    const float* __restrict__ nn, const float* __restrict__ Wn,
    const float* __restrict__ bn, const float* __restrict__ Wedge,
    const float* __restrict__ gx, const float* __restrict__ bx,
    float* __restrict__ a_row, float* __restrict__ a_col,
    float* __restrict__ out_node)
{
  int bi = blockIdx.x; int t = threadIdx.x;
  int w = t >> 6, lane = t & 63;
  __shared__ float nl[64];
  __shared__ float rl[256];
  __shared__ float red[4];
  if (t < 64) nl[t] = nn[(size_t)bi*D_ + t];
  __syncthreads();
  float acc = bn[t];
  #pragma unroll 4
  for (int d = 0; d < 64; ++d) acc += nl[d]*Wn[(size_t)d*IN_ + t];
  rl[t] = acc;
  float y = emb_node[(size_t)bi*IN_ + t]*node_mask[bi] + acc;
  float s = wave_sum64(y);
  if (lane == 0) red[w] = s;
  __syncthreads();
  float mean = (red[0]+red[1]+red[2]+red[3]) * (1.f/256.f);
  float dv = y - mean;
  float s2 = wave_sum64(dv*dv);
  __syncthreads();
  if (lane == 0) red[w] = s2;
  __syncthreads();
  float var = (red[0]+red[1]+red[2]+red[3]) * (1.f/256.f);
  out_node[(size_t)bi*IN_ + t] = dv * (1.0f/sqrtf(var + LN_EPS_)) * gx[t] + bx[t];
  float ar = 0.f, ac = 0.f;
  #pragma unroll 4
  for (int k = 0; k < 256; ++k){
    float rv = rl[k];
    ar += rv*Wedge[(size_t)k*IN_ + t];
    ac += rv*Wedge[(size_t)(k + 256)*IN_ + t];
  }
  a_row[(size_t)bi*IN_ + t] = ar;
  a_col[(size_t)bi*IN_ + t] = ac;
}

// K5: out_edge = LN(m*(xe_raw + xe@W3) + a_row + a_col + bedge) via split-bf16 MFMA
__global__ __launch_bounds__(512) void k5_edge(
    const float* __restrict__ emb_edge, const float* __restrict__ node_mask,
    const unsigned short* __restrict__ W3T_hi, const unsigned short* __restrict__ W3T_lo,
    const float* __restrict__ a_row, const float* __restrict__ a_col,
    const float* __restrict__ bedge, const float* __restrict__ ge,
    const float* __restrict__ be, float* __restrict__ out_edge)
{
  int blk = blockIdx.x;
  int b = blk >> 8, i = blk & 255;
  size_t f0 = (size_t)blk * N_;
  int tid = threadIdx.x, w = tid >> 6, l = tid & 63, h = l >> 5, ln = l & 31;

  __shared__ unsigned short Ah[256*LSTR], Al[256*LSTR], Bh[256*LSTR], Bl[256*LSTR];
  __shared__ float arow_l[256], mj_l[256], bed_l[256], ge_l[256], be_l[256];

  if (tid < 256){
    arow_l[tid] = a_row[((size_t)(b*N_ + i))*IN_ + tid];
    mj_l[tid]   = node_mask[(b<<8) + tid];
    bed_l[tid]  = bedge[tid];
    ge_l[tid]   = ge[tid];
    be_l[tid]   = be[tid];
  }

  f32x16 acc[8];
  #pragma unroll
  for (int ct = 0; ct < 8; ++ct)
    #pragma unroll
    for (int e = 0; e < 16; ++e) acc[ct][e] = 0.f;

  int r = tid & 255, sub = tid >> 8;
  const float* xrow = emb_edge + (f0 + r)*IN_;
  const unsigned short* bsrcp = (sub ? W3T_lo : W3T_hi) + (size_t)r*IN_;
  unsigned short* bdst = sub ? Bl : Bh;

  for (int k0 = 0; k0 < IN_; k0 += 16){
    __syncthreads();
    {
      uint4 v0 = *(const uint4*)(bsrcp + k0);
      uint4 v1 = *(const uint4*)(bsrcp + k0 + 8);
      *(uint4*)&bdst[swoff(r, 0)] = v0;
      *(uint4*)&bdst[swoff(r, 1)] = v1;
      const float4* asrc = (const float4*)(xrow + k0 + sub*8);
      float4 q0 = asrc[0], q1 = asrc[1];
      float xs[8] = {q0.x,q0.y,q0.z,q0.w,q1.x,q1.y,q1.z,q1.w};
      U8 hh, ll;
      #pragma unroll
      for (int q = 0; q < 8; ++q){
        unsigned short hb = f2bf(xs[q]);
        hh.u[q] = hb;
        ll.u[q] = f2bf(xs[q] - bf2f(hb));
      }
      *(uint4*)&Ah[swoff(r, sub)] = hh.v;
      *(uint4*)&Al[swoff(r, sub)] = ll.v;
    }
    __syncthreads();
    {
      int g = h;
      bf16x8 ah  = *(const bf16x8*)&Ah[swoff(w*32 + ln, g)];
      bf16x8 al_ = *(const bf16x8*)&Al[swoff(w*32 + ln, g)];
      #pragma unroll
      for (int ct = 0; ct < 8; ++ct){
        bf16x8 bh  = *(const bf16x8*)&Bh[swoff(ct*32 + ln, g)];
        bf16x8 bl_ = *(const bf16x8*)&Bl[swoff(ct*32 + ln, g)];
        acc[ct] = mm(ah,  bh,  acc[ct]);
        acc[ct] = mm(ah,  bl_, acc[ct]);
        acc[ct] = mm(al_, bh,  acc[ct]);
      }
    }
  }

  float mi = node_mask[(b<<8) + i];
  #pragma unroll
  for (int rg = 0; rg < 16; ++rg){
    int jl = w*32 + (rg&3) + ((rg>>2)<<3) + (h<<2);
    float m = mi * mj_l[jl];
    size_t f = f0 + jl;
    const float* xr = emb_edge + f*IN_;
    const float* acj = a_col + ((size_t)(b*N_ + jl))*IN_;
    float y[8]; float s = 0.f;
    #pragma unroll
    for (int ct = 0; ct < 8; ++ct){
      int col = ct*32 + ln;
      y[ct] = fmaf(m, xr[col] + acc[ct][rg], arow_l[col] + acj[col] + bed_l[col]);
      s += y[ct];
    }
    s += __shfl_xor(s, 1); s += __shfl_xor(s, 2); s += __shfl_xor(s, 4);
    s += __shfl_xor(s, 8); s += __shfl_xor(s, 16);
    float mean = s * (1.f/256.f);
    float s2 = 0.f;
    #pragma unroll
    for (int ct = 0; ct < 8; ++ct){ float d = y[ct] - mean; s2 = fmaf(d, d, s2); }
    s2 += __shfl_xor(s2, 1); s2 += __shfl_xor(s2, 2); s2 += __shfl_xor(s2, 4);
    s2 += __shfl_xor(s2, 8); s2 += __shfl_xor(s2, 16);
    float rstd = rsqrtf(s2*(1.f/256.f) + LN_EPS_);
    #pragma unroll
    for (int ct = 0; ct < 8; ++ct){
      int col = ct*32 + ln;
      out_edge[f*IN_ + col] = (y[ct] - mean)*rstd*ge_l[col] + be_l[col];
    }
  }
}

extern "C" void kernel_launch(void* const* d_in, const int* in_sizes, int n_in,
                              void* d_out, int out_size, void* d_ws, size_t ws_size,
                              hipStream_t stream)
{
  const float* emb_node  = (const float*)d_in[0];
  const float* emb_edge  = (const float*)d_in[1];
  const float* adj       = (const float*)d_in[2];
  const float* node_mask = (const float*)d_in[3];
  const float* Ws    = (const float*)d_in[4];
  const float* Wt    = (const float*)d_in[5];
  const float* We    = (const float*)d_in[6];
  const float* attn  = (const float*)d_in[7];
  const float* Wn    = (const float*)d_in[8];
  const float* bn    = (const float*)d_in[9];
  const float* Wedge = (const float*)d_in[10];
  const float* bedge = (const float*)d_in[11];
  const float* gx    = (const float*)d_in[12];
  const float* bx    = (const float*)d_in[13];
  const float* ge    = (const float*)d_in[14];
  const float* be    = (const float*)d_in[15];

  float* ws     = (float*)d_ws;
  float* hs     = ws;                   // 262144
  float* ht     = hs + 262144;          // 262144
  float* htT    = ht + 262144;          // 262144
  float* scores = htT + 262144;         // 1048576  [B][H][N][N]
  float* invd   = scores + 1048576;     // 4096
  float* nn     = invd + 4096;          // 32768
  float* a_row  = nn + 32768;           // 131072
  float* a_col  = a_row + 131072;       // 131072
  unsigned short* WeT_hi = (unsigned short*)(a_col + 131072);  // 131072 us
  unsigned short* WeT_lo = WeT_hi + 131072;
  unsigned short* W3T_hi = WeT_lo + 131072;                    // 65536 us
  unsigned short* W3T_lo = W3T_hi + 65536;

  float* out_node = (float*)d_out;
  float* out_edge = out_node + (size_t)B_*N_*IN_;

  k0_wprep<<<768, 256, 0, stream>>>(We, Wedge, WeT_hi, WeT_lo, W3T_hi, W3T_lo);
  k1_hst  <<<128, 512, 0, stream>>>(emb_node, node_mask, Ws, Wt, hs, ht, htT);
  k2_scores<<<dim3(B_*N_, 2), 512, 0, stream>>>(emb_edge, adj, node_mask,
                                                WeT_hi, WeT_lo, hs, htT, attn, scores);
  k3a_denom<<<(B_*H_*N_)/4, 256, 0, stream>>>(scores, invd);
  k3b_nn  <<<B_*N_, 256, 0, stream>>>(scores, invd, ht, nn);
  k4_node <<<B_*N_, 256, 0, stream>>>(emb_node, node_mask, nn, Wn, bn, Wedge,
                                      gx, bx, a_row, a_col, out_node);
  k5_edge <<<B_*N_*N_/64/4, 512, 0, stream>>>(emb_edge, node_mask, W3T_hi, W3T_lo,
                                              a_row, a_col, bedge, ge, be, out_edge);
}